// Round 11
// baseline (127.139 us; speedup 1.0000x reference)
//
#include <hip/hip_runtime.h>
#include <hip/hip_bf16.h>

// B=2048, T=128, I=130, H=10, 3H=30, D1=20
// Round-11: T3/T4 (counted-vmcnt, never-drain) pipeline for xi_gemm.
//   r7-r10 invariant: xi_gemm ~= FETCH/1.2TB/s with all pipes idle -> the
//   2-phase stage/drain structure (m233: ~72% overhead) was the cap.
//   Now: global_load_lds width=16 direct to LDS (2 buffers/wave, linear,
//   zero-conflict mapping from r7), hand-counted s_waitcnt vmcnt(N):
//     t=0: vmcnt(9)  (tile1's 9 loads stay in flight)
//     t=1..6: vmcnt(17)  (9 loads + 8 stores in flight)
//     t=7: vmcnt(8)
//   each + sched_barrier(0); lgkmcnt(0)+sched_barrier before overwriting the
//   just-read buffer. Compute/fragments/stores = r7 verified path.
//   prep_w + gru_scan unchanged (r7/r9). Fallback: monolithic kernel.

#define BB 2048
#define TT 128
#define II 130
#define ROWS_PER_GRU (BB * TT)          // 262144
#define ROWS_TOTAL   (2 * ROWS_PER_GRU) // 524288
#define XI_BYTES ((size_t)ROWS_TOTAL * 30 * sizeof(float))   // 62,914,560
#define FRAG_U4_PER_GRU 1024            // 2t * 4q * 2p * 64 lanes

typedef __attribute__((ext_vector_type(8))) short short8v;  // 8 bf16
typedef __attribute__((ext_vector_type(4))) float f32x4;

union U8 { unsigned u[4]; short8v v; };
union SU { uint4 u; short8v v; };

__device__ __forceinline__ float sigmoidf_fast(float x) {
    return __fdividef(1.f, 1.f + __expf(-x));
}
__device__ __forceinline__ float tanhf_fast(float x) {
    float ax = fabsf(x);
    float e = __expf(-2.f * ax);
    float t = __fdividef(1.f - e, 1.f + e);
    return copysignf(t, x);
}

// truncation split of 2 fp32 -> packed bf16-hi pair + bf16-lo pair
__device__ __forceinline__ void split2(float x0, float x1,
                                       unsigned& hi, unsigned& lo) {
    unsigned u0 = __float_as_uint(x0), u1 = __float_as_uint(x1);
    hi = (u0 >> 16) | (u1 & 0xffff0000u);
    float f0 = __uint_as_float(u0 & 0xffff0000u);
    float f1 = __uint_as_float(u1 & 0xffff0000u);
    unsigned l0 = __float_as_uint(x0 - f0);
    unsigned l1 = __float_as_uint(x1 - f1);
    lo = (l0 >> 16) | (l1 & 0xffff0000u);
}

__device__ __forceinline__ void load_split(const float* __restrict__ p,
                                           short8v& hi, short8v& lo) {
    U8 H, L;
    #pragma unroll
    for (int i = 0; i < 4; ++i) {
        const float2 xy = *(const float2*)(p + 2 * i);
        split2(xy.x, xy.y, H.u[i], L.u[i]);
    }
    hi = H.v; lo = L.v;
}

__device__ __forceinline__ void split4(const float2* a,
                                       short8v& hi, short8v& lo) {
    U8 H, L;
    #pragma unroll
    for (int i = 0; i < 4; ++i) split2(a[i].x, a[i].y, H.u[i], L.u[i]);
    hi = H.v; lo = L.v;
}

// ---------------- prep_w: B fragments, once ----------------
__global__ void prep_w(const float* __restrict__ ruWih,
                       const float* __restrict__ enWih,
                       uint4* __restrict__ frags)
{
    const int tid  = threadIdx.x;      // 128 threads = 2 waves
    const int gru  = tid >> 6;
    const int lane = tid & 63;
    const int lr   = lane & 15;
    const int lk   = lane >> 4;
    const float* __restrict__ Wf = gru ? enWih : ruWih;
    uint4* __restrict__ fb = frags + gru * FRAG_U4_PER_GRU;
    #pragma unroll
    for (int t = 0; t < 2; ++t) {
        const int g  = 16 * t + lr;
        const int gv = (g < 30) ? g : 0;
        #pragma unroll
        for (int q = 0; q < 4; ++q) {
            short8v hi, lo;
            load_split(Wf + (long)gv * II + 32 * q + 8 * lk, hi, lo);
            if (g >= 30) {                 // mask cols 30,31
                const short8v z = {0,0,0,0,0,0,0,0};
                hi = z; lo = z;
            }
            SU sh, sl; sh.v = hi; sl.v = lo;
            fb[((t * 4 + q) * 2 + 0) * 64 + lane] = sh.u;
            fb[((t * 4 + q) * 2 + 1) * 64 + lane] = sl.u;
        }
    }
}

// ---------------- Phase 1: counted-vmcnt MFMA pipeline ----------------
#define MFMA16(A, B, C) __builtin_amdgcn_mfma_f32_16x16x32_bf16((A), (B), (C), 0, 0, 0)

#define VMWAIT_(N) asm volatile("s_waitcnt vmcnt(" #N ")" ::: "memory")
#define VMWAIT(N) do { VMWAIT_(N); __builtin_amdgcn_sched_barrier(0); } while (0)
#define LGKMWAIT0 do { asm volatile("s_waitcnt lgkmcnt(0)" ::: "memory"); \
                       __builtin_amdgcn_sched_barrier(0); } while (0)

// 9 global_load_lds issues: one 16x130-f32 tile -> linear LDS buffer.
// LDS dest is WAVE-UNIFORM base; HW adds lane*16. Global src is per-lane.
__device__ __forceinline__ void issue_tile(const float4* __restrict__ s,
                                           float4* d, int lane) {
    #pragma unroll
    for (int c = 0; c < 8; ++c)
        __builtin_amdgcn_global_load_lds(
            (const __attribute__((address_space(1))) unsigned*)(s + 64 * c + lane),
            (__attribute__((address_space(3))) unsigned*)(d + 64 * c), 16, 0, 0);
    if (lane < 8)
        __builtin_amdgcn_global_load_lds(
            (const __attribute__((address_space(1))) unsigned*)(s + 512 + lane),
            (__attribute__((address_space(3))) unsigned*)(d + 512), 16, 0, 0);
}

__global__ __launch_bounds__(128)
void xi_gemm(const float* __restrict__ ru, const float* __restrict__ en,
             const float* __restrict__ ruWih, const float* __restrict__ rubih,
             const float* __restrict__ enWih, const float* __restrict__ enbih,
             const uint4* __restrict__ frags, float* __restrict__ xi)
{
    const int tid  = threadIdx.x;
    const int wv   = tid >> 6;           // 2 waves/block
    const int lane = tid & 63;
    const int lr   = lane & 15;          // A-row slot / C-col
    const int lk   = lane >> 4;          // k-subblock / C-row group
    const int w    = blockIdx.x * 2 + wv;            // wave 0..4095
    const int gru  = (w >= 2048);
    const long row0 = (long)(w & 2047) * 128;        // 8 tiles x 16 rows

    const float* __restrict__ X   = gru ? en    : ru;
    const float* __restrict__ Wf  = gru ? enWih : ruWih;
    const float* __restrict__ bih = gru ? enbih : rubih;

    // ---- prologue loads FIRST in vmcnt order: B frags + bias + tail wts ----
    const uint4* __restrict__ fb = frags + gru * FRAG_U4_PER_GRU;
    short8v Bhi[2][4], Blo[2][4];
    #pragma unroll
    for (int t = 0; t < 2; ++t)
        #pragma unroll
        for (int q = 0; q < 4; ++q) {
            SU sh, sl;
            sh.u = fb[((t * 4 + q) * 2 + 0) * 64 + lane];
            sl.u = fb[((t * 4 + q) * 2 + 1) * 64 + lane];
            Bhi[t][q] = sh.v; Blo[t][q] = sl.v;
        }
    const int gv1 = (16 + lr < 30) ? 16 + lr : 0;
    const float bias0 = bih[lr];
    const float bias1 = bih[gv1];
    const float2 w0 = *(const float2*)(Wf + (long)lr  * II + 128);
    const float2 w1 = *(const float2*)(Wf + (long)gv1 * II + 128);

    // ---- double-buffered per-wave LDS (linear, zero-conflict per r7) ----
    __shared__ __align__(16) float ldsbuf[2][2][16 * II];  // 33,280 B/block
    float4* Bu[2] = { (float4*)ldsbuf[wv][0], (float4*)ldsbuf[wv][1] };

    const float4* __restrict__ src = (const float4*)(X + row0 * II);
    const long gb = (long)gru * ROWS_PER_GRU;

    issue_tile(src, Bu[0], lane);               // gll tile 0 (9 ops)
    issue_tile(src + 520, Bu[1], lane);         // gll tile 1 (9 ops)

    #pragma unroll
    for (int t = 0; t < 8; ++t) {
        // counted wait: tile t's 9 loads complete; keep the rest in flight
        if (t == 0)      VMWAIT(9);
        else if (t == 7) VMWAIT(8);
        else             VMWAIT(17);            // 9 loads + 8 stores in flight

        const float* __restrict__ buf = (const float*)ldsbuf[wv][t & 1];

        // ds_reads for the whole tile into registers
        float2 A[4][4];
        #pragma unroll
        for (int q = 0; q < 4; ++q) {
            const float* __restrict__ ap = buf + lr * II + 32 * q + 8 * lk;
            #pragma unroll
            for (int j = 0; j < 4; ++j) A[q][j] = *(const float2*)(ap + 2 * j);
        }
        float2 tl[4];
        #pragma unroll
        for (int r = 0; r < 4; ++r)
            tl[r] = *(const float2*)(buf + (4 * lk + r) * II + 128);

        LGKMWAIT0;                               // reads done before overwrite

        if (t + 2 < 8)                           // refill just-consumed buffer
            issue_tile(src + 520 * (t + 2), Bu[t & 1], lane);

        // ---- compute: 24 MFMA, 3-term bf16 emulation (verified r6-r10) ----
        f32x4 a0 = (f32x4){bias0, bias0, bias0, bias0};
        f32x4 a1 = (f32x4){bias1, bias1, bias1, bias1};
        #pragma unroll
        for (int q = 0; q < 4; ++q) {
            short8v ahi, alo;
            split4(A[q], ahi, alo);
            a0 = MFMA16(ahi, Bhi[0][q], a0);
            a0 = MFMA16(ahi, Blo[0][q], a0);
            a0 = MFMA16(alo, Bhi[0][q], a0);
            a1 = MFMA16(ahi, Bhi[1][q], a1);
            a1 = MFMA16(ahi, Blo[1][q], a1);
            a1 = MFMA16(alo, Bhi[1][q], a1);
        }

        // ---- k-tail + store. C: col=lr, row-in-tile=4*lk+r ----
        #pragma unroll
        for (int r = 0; r < 4; ++r) {
            const long rr = row0 + 16 * t + 4 * lk + r;
            float* __restrict__ xo = xi + (gb + rr) * 30;
            xo[lr] = a0[r] + tl[r].x * w0.x + tl[r].y * w0.y;
            if (lr < 14)
                xo[16 + lr] = a1[r] + tl[r].x * w1.x + tl[r].y * w1.y;
        }
    }
}

// ---------------- Phase 2: recurrent scan (r7 version) ----------------
__global__ __launch_bounds__(256, 4)
void gru_scan(const float* __restrict__ xi,
              const float* __restrict__ ruWhh, const float* __restrict__ rubhh,
              const float* __restrict__ enWhh, const float* __restrict__ enbhh,
              const float* __restrict__ W1, const float* __restrict__ b1,
              const float* __restrict__ W2, const float* __restrict__ b2,
              float* __restrict__ out)
{
    const int tid  = threadIdx.x;
    const int wv   = tid >> 6;
    const int lane = tid & 63;
    const int c    = lane >> 5;
    const int k    = lane & 31;
    const int kq   = (k < 10) ? k : 0;
    const int chain = (blockIdx.x * 4 + wv) * 2 + c;
    const int gru   = chain >> 11;
    const int b     = chain & (BB - 1);

    const float* __restrict__ Whh = gru ? enWhh : ruWhh;
    const float* __restrict__ bhh = gru ? enbhh : rubhh;

    float whhR[10], whhZ[10], whhN[10];
    #pragma unroll
    for (int j = 0; j < 10; ++j) {
        whhR[j] = Whh[kq * 10 + j];
        whhZ[j] = Whh[(10 + kq) * 10 + j];
        whhN[j] = Whh[(20 + kq) * 10 + j];
    }
    const float bR = bhh[kq], bZ = bhh[10 + kq], bN = bhh[20 + kq];

    __shared__ __align__(16) float lds[4][32];
    float* __restrict__ H = lds[wv] + c * 16;
    if (k < 12) H[k] = 0.f;
    float hown = 0.f;

    const float* __restrict__ xrow =
        xi + ((long)gru * ROWS_PER_GRU + (long)b * TT) * 30;

    float xR0 = xrow[kq],      xZ0 = xrow[10 + kq],  xN0 = xrow[20 + kq];
    float xR1 = xrow[30 + kq], xZ1 = xrow[40 + kq],  xN1 = xrow[50 + kq];

    for (int t = 0; t < TT; ++t) {
        const float xR = xR0, xZ = xZ0, xN = xN0;
        xR0 = xR1; xZ0 = xZ1; xN0 = xN1;
        {
            const int tn = (t + 2 < TT) ? t + 2 : TT - 1;
            const float* __restrict__ xp = xrow + (long)tn * 30;
            xR1 = xp[kq]; xZ1 = xp[10 + kq]; xN1 = xp[20 + kq];
        }

        const float4 h03 = *(const float4*)(H);
        const float4 h47 = *(const float4*)(H + 4);
        const float2 h89 = *(const float2*)(H + 8);

        float gr = bR, gz = bZ, gn = bN;
        gr = fmaf(whhR[0], h03.x, gr); gz = fmaf(whhZ[0], h03.x, gz); gn = fmaf(whhN[0], h03.x, gn);
        gr = fmaf(whhR[1], h03.y, gr); gz = fmaf(whhZ[1], h03.y, gz); gn = fmaf(whhN[1], h03.y, gn);
        gr = fmaf(whhR[2], h03.z, gr); gz = fmaf(whhZ[2], h03.z, gz); gn = fmaf(whhN[2], h03.z, gn);
        gr = fmaf(whhR[3], h03.w, gr); gz = fmaf(whhZ[3], h03.w, gz); gn = fmaf(whhN[3], h03.w, gn);
        gr = fmaf(whhR[4], h47.x, gr); gz = fmaf(whhZ[4], h47.x, gz); gn = fmaf(whhN[4], h47.x, gn);
        gr = fmaf(whhR[5], h47.y, gr); gz = fmaf(whhZ[5], h47.y, gz); gn = fmaf(whhN[5], h47.y, gn);
        gr = fmaf(whhR[6], h47.z, gr); gz = fmaf(whhZ[6], h47.z, gz); gn = fmaf(whhN[6], h47.z, gn);
        gr = fmaf(whhR[7], h47.w, gr); gz = fmaf(whhZ[7], h47.w, gz); gn = fmaf(whhN[7], h47.w, gn);
        gr = fmaf(whhR[8], h89.x, gr); gz = fmaf(whhZ[8], h89.x, gz); gn = fmaf(whhN[8], h89.x, gn);
        gr = fmaf(whhR[9], h89.y, gr); gz = fmaf(whhZ[9], h89.y, gz); gn = fmaf(whhN[9], h89.y, gn);

        const float r = sigmoidf_fast(xR + gr);
        const float z = sigmoidf_fast(xZ + gz);
        const float n = tanhf_fast(xN + r * gn);
        hown = fmaf(z, hown - n, n);
        if (k < 10) H[k] = hown;
    }

    float val = 0.f;
    if (k < 10) {
        float v = 0.f;
        #pragma unroll
        for (int d = 0; d < 20; ++d)
            v = fmaf(W2[d], W1[d * 20 + gru * 10 + k], v);
        val = v * hown;
        if (k == 0 && gru == 0) {
            float c0 = b2[0];
            #pragma unroll
            for (int d = 0; d < 20; ++d) c0 = fmaf(W2[d], b1[d], c0);
            val += c0;
        }
    }
    val += __shfl_xor(val, 8);
    val += __shfl_xor(val, 4);
    val += __shfl_xor(val, 2);
    val += __shfl_xor(val, 1);
    if (k == 0) atomicAdd(&out[b], val);
}

// ---------------- Fallback: monolithic kernel ----------------
__global__ __launch_bounds__(256, 4)
void gru_fused(const float* __restrict__ ru, const float* __restrict__ en,
               const float* __restrict__ ruWih, const float* __restrict__ ruWhh,
               const float* __restrict__ rubih, const float* __restrict__ rubhh,
               const float* __restrict__ enWih, const float* __restrict__ enWhh,
               const float* __restrict__ enbih, const float* __restrict__ enbhh,
               const float* __restrict__ W1, const float* __restrict__ b1,
               const float* __restrict__ W2, const float* __restrict__ b2,
               float* __restrict__ out)
{
    const int tid  = threadIdx.x;
    const int wv   = tid >> 6;
    const int lane = tid & 63;
    const int g    = lane & 31;
    const int h    = lane >> 5;
    const int wid  = blockIdx.x * 4 + wv;
    const int gru  = wid >> 11;
    const int b    = wid & (BB - 1);

    const float* __restrict__ x   = gru ? en    : ru;
    const float* __restrict__ Wih = gru ? enWih : ruWih;
    const float* __restrict__ Whh = gru ? enWhh : ruWhh;
    const float* __restrict__ bih = gru ? enbih : rubih;
    const float* __restrict__ bhh = gru ? enbhh : rubhh;

    __shared__ __align__(16) float lds[4][176];
    float* __restrict__ X    = lds[wv];
    float* __restrict__ PRE  = X + 132;
    float* __restrict__ Hbuf = X + 164;

    const int gq = (g < 30) ? g : 0;
    float wih[64];
    #pragma unroll
    for (int j = 0; j < 64; ++j) wih[j] = Wih[gq * II + h * 64 + j];
    const float w_e = Wih[gq * II + 128 + h];
    float whh[10];
    #pragma unroll
    for (int k = 0; k < 10; ++k) whh[k] = Whh[gq * 10 + k];
    const float bihg = bih[gq];
    const float bhhg = bhh[gq];

    if (lane < 12) Hbuf[lane] = 0.f;
    float hown = 0.f;

    const float* __restrict__ xrow = x + (size_t)b * (TT * II);
    float xa = xrow[lane];
    float xb = xrow[64 + lane];
    float xc = (lane < 2) ? xrow[128 + lane] : 0.f;

    for (int t = 0; t < TT; ++t) {
        X[lane] = xa;
        X[64 + lane] = xb;
        if (lane < 2) X[128 + lane] = xc;
        {
            const int tn = (t < TT - 1) ? t + 1 : t;
            const float* __restrict__ xn = xrow + (size_t)tn * II;
            xa = xn[lane];
            xb = xn[64 + lane];
            xc = (lane < 2) ? xn[128 + lane] : 0.f;
        }
        const float4 h03 = *(const float4*)(Hbuf);
        const float4 h47 = *(const float4*)(Hbuf + 4);
        const float2 h89 = *(const float2*)(Hbuf + 8);
        float gh0 = fmaf(whh[0], h03.x, bhhg);
        float gh1 = whh[1] * h03.y;
        gh0 = fmaf(whh[2], h03.z, gh0);
        gh1 = fmaf(whh[3], h03.w, gh1);
        gh0 = fmaf(whh[4], h47.x, gh0);
        gh1 = fmaf(whh[5], h47.y, gh1);
        gh0 = fmaf(whh[6], h47.z, gh0);
        gh1 = fmaf(whh[7], h47.w, gh1);
        gh0 = fmaf(whh[8], h89.x, gh0);
        gh1 = fmaf(whh[9], h89.y, gh1);
        const float gh = gh0 + gh1;

        float s0 = 0.f, s1 = 0.f, s2 = 0.f, s3 = 0.f;
        const float4* __restrict__ xb4 = (const float4*)(X + h * 64);
        #pragma unroll
        for (int c = 0; c < 16; ++c) {
            const float4 v = xb4[c];
            s0 = fmaf(wih[4 * c + 0], v.x, s0);
            s1 = fmaf(wih[4 * c + 1], v.y, s1);
            s2 = fmaf(wih[4 * c + 2], v.z, s2);
            s3 = fmaf(wih[4 * c + 3], v.w, s3);
        }
        float s = (s0 + s1) + (s2 + s3);
        s = fmaf(w_e, X[128 + h], s);
        s += __shfl_xor(s, 32);

        const float xiv = s + bihg;
        const float pre = xiv + gh;
        if (lane < 30) PRE[lane] = pre;
        const float rpre = PRE[(g - 20) & 31];
        const float zpre = PRE[(g - 10) & 31];
        const float r = sigmoidf_fast(rpre);
        const float z = sigmoidf_fast(zpre);
        const float n = tanhf_fast(xiv + r * gh);
        const float hnew = (1.f - z) * n + z * hown;
        hown = hnew;
        if (lane >= 20 && lane < 30) Hbuf[lane - 20] = hnew;
    }

    float val = 0.f;
    if (lane < 10) {
        const float hk = Hbuf[lane];
        float v = 0.f;
        #pragma unroll
        for (int d = 0; d < 20; ++d)
            v = fmaf(W2[d], W1[d * 20 + gru * 10 + lane], v);
        val = v * hk;
        if (lane == 0 && gru == 0) {
            float c0 = b2[0];
            #pragma unroll
            for (int d = 0; d < 20; ++d) c0 = fmaf(W2[d], b1[d], c0);
            val += c0;
        }
    }
    #pragma unroll
    for (int o = 32; o > 0; o >>= 1) val += __shfl_xor(val, o);
    if (lane == 0) atomicAdd(&out[b], val);
}

extern "C" void kernel_launch(void* const* d_in, const int* in_sizes, int n_in,
                              void* d_out, int out_size, void* d_ws, size_t ws_size,
                              hipStream_t stream) {
    (void)in_sizes; (void)n_in;
    const float* ru    = (const float*)d_in[0];
    const float* en    = (const float*)d_in[1];
    const float* ruWih = (const float*)d_in[2];
    const float* ruWhh = (const float*)d_in[3];
    const float* rubih = (const float*)d_in[4];
    const float* rubhh = (const float*)d_in[5];
    const float* enWih = (const float*)d_in[6];
    const float* enWhh = (const float*)d_in[7];
    const float* enbih = (const float*)d_in[8];
    const float* enbhh = (const float*)d_in[9];
    const float* W1    = (const float*)d_in[10];
    const float* b1    = (const float*)d_in[11];
    const float* W2    = (const float*)d_in[12];
    const float* b2    = (const float*)d_in[13];
    float* out = (float*)d_out;

    hipMemsetAsync(d_out, 0, (size_t)out_size * sizeof(float), stream);

    const size_t frag_bytes = 2 * FRAG_U4_PER_GRU * sizeof(uint4);  // 32 KB
    if (ws_size >= XI_BYTES + frag_bytes) {
        float* xi = (float*)d_ws;
        uint4* frags = (uint4*)((char*)d_ws + XI_BYTES);
        prep_w<<<dim3(1), dim3(128), 0, stream>>>(ruWih, enWih, frags);
        // 4096 waves x 8 tiles x 16 rows; 2 waves/block -> 2048 blocks
        xi_gemm<<<dim3(2048), dim3(128), 0, stream>>>(
            ru, en, ruWih, rubih, enWih, enbih, frags, xi);
        gru_scan<<<dim3(512), dim3(256), 0, stream>>>(
            xi, ruWhh, rubhh, enWhh, enbhh, W1, b1, W2, b2, out);
    } else {
        gru_fused<<<dim3(1024), dim3(256), 0, stream>>>(
            ru, en, ruWih, ruWhh, rubih, rubhh,
            enWih, enWhh, enbih, enbhh, W1, b1, W2, b2, out);
    }
}

// Round 12
// 126.870 us; speedup vs baseline: 1.0021x; 1.0021x over previous
//
#include <hip/hip_runtime.h>
#include <hip/hip_bf16.h>

// B=2048, T=128, I=130, H=10, 3H=30, D1=20
// Round-11: T3/T4 (counted-vmcnt, never-drain) pipeline for xi_gemm.
//   r7-r10 invariant: xi_gemm ~= FETCH/1.2TB/s with all pipes idle -> the
//   2-phase stage/drain structure (m233: ~72% overhead) was the cap.
//   Now: global_load_lds width=16 direct to LDS (2 buffers/wave, linear,
//   zero-conflict mapping from r7), hand-counted s_waitcnt vmcnt(N):
//     t=0: vmcnt(9)  (tile1's 9 loads stay in flight)
//     t=1..6: vmcnt(17)  (9 loads + 8 stores in flight)
//     t=7: vmcnt(8)
//   each + sched_barrier(0); lgkmcnt(0)+sched_barrier before overwriting the
//   just-read buffer. Compute/fragments/stores = r7 verified path.
//   prep_w + gru_scan unchanged (r7/r9). Fallback: monolithic kernel.

#define BB 2048
#define TT 128
#define II 130
#define ROWS_PER_GRU (BB * TT)          // 262144
#define ROWS_TOTAL   (2 * ROWS_PER_GRU) // 524288
#define XI_BYTES ((size_t)ROWS_TOTAL * 30 * sizeof(float))   // 62,914,560
#define FRAG_U4_PER_GRU 1024            // 2t * 4q * 2p * 64 lanes

typedef __attribute__((ext_vector_type(8))) short short8v;  // 8 bf16
typedef __attribute__((ext_vector_type(4))) float f32x4;

union U8 { unsigned u[4]; short8v v; };
union SU { uint4 u; short8v v; };

__device__ __forceinline__ float sigmoidf_fast(float x) {
    return __fdividef(1.f, 1.f + __expf(-x));
}
__device__ __forceinline__ float tanhf_fast(float x) {
    float ax = fabsf(x);
    float e = __expf(-2.f * ax);
    float t = __fdividef(1.f - e, 1.f + e);
    return copysignf(t, x);
}

// truncation split of 2 fp32 -> packed bf16-hi pair + bf16-lo pair
__device__ __forceinline__ void split2(float x0, float x1,
                                       unsigned& hi, unsigned& lo) {
    unsigned u0 = __float_as_uint(x0), u1 = __float_as_uint(x1);
    hi = (u0 >> 16) | (u1 & 0xffff0000u);
    float f0 = __uint_as_float(u0 & 0xffff0000u);
    float f1 = __uint_as_float(u1 & 0xffff0000u);
    unsigned l0 = __float_as_uint(x0 - f0);
    unsigned l1 = __float_as_uint(x1 - f1);
    lo = (l0 >> 16) | (l1 & 0xffff0000u);
}

__device__ __forceinline__ void load_split(const float* __restrict__ p,
                                           short8v& hi, short8v& lo) {
    U8 H, L;
    #pragma unroll
    for (int i = 0; i < 4; ++i) {
        const float2 xy = *(const float2*)(p + 2 * i);
        split2(xy.x, xy.y, H.u[i], L.u[i]);
    }
    hi = H.v; lo = L.v;
}

__device__ __forceinline__ void split4(const float2* a,
                                       short8v& hi, short8v& lo) {
    U8 H, L;
    #pragma unroll
    for (int i = 0; i < 4; ++i) split2(a[i].x, a[i].y, H.u[i], L.u[i]);
    hi = H.v; lo = L.v;
}

// ---------------- prep_w: B fragments, once ----------------
__global__ void prep_w(const float* __restrict__ ruWih,
                       const float* __restrict__ enWih,
                       uint4* __restrict__ frags)
{
    const int tid  = threadIdx.x;      // 128 threads = 2 waves
    const int gru  = tid >> 6;
    const int lane = tid & 63;
    const int lr   = lane & 15;
    const int lk   = lane >> 4;
    const float* __restrict__ Wf = gru ? enWih : ruWih;
    uint4* __restrict__ fb = frags + gru * FRAG_U4_PER_GRU;
    #pragma unroll
    for (int t = 0; t < 2; ++t) {
        const int g  = 16 * t + lr;
        const int gv = (g < 30) ? g : 0;
        #pragma unroll
        for (int q = 0; q < 4; ++q) {
            short8v hi, lo;
            load_split(Wf + (long)gv * II + 32 * q + 8 * lk, hi, lo);
            if (g >= 30) {                 // mask cols 30,31
                const short8v z = {0,0,0,0,0,0,0,0};
                hi = z; lo = z;
            }
            SU sh, sl; sh.v = hi; sl.v = lo;
            fb[((t * 4 + q) * 2 + 0) * 64 + lane] = sh.u;
            fb[((t * 4 + q) * 2 + 1) * 64 + lane] = sl.u;
        }
    }
}

// ---------------- Phase 1: counted-vmcnt MFMA pipeline ----------------
#define MFMA16(A, B, C) __builtin_amdgcn_mfma_f32_16x16x32_bf16((A), (B), (C), 0, 0, 0)

#define VMWAIT_(N) asm volatile("s_waitcnt vmcnt(" #N ")" ::: "memory")
#define VMWAIT(N) do { VMWAIT_(N); __builtin_amdgcn_sched_barrier(0); } while (0)
#define LGKMWAIT0 do { asm volatile("s_waitcnt lgkmcnt(0)" ::: "memory"); \
                       __builtin_amdgcn_sched_barrier(0); } while (0)

// 9 global_load_lds issues: one 16x130-f32 tile -> linear LDS buffer.
// LDS dest is WAVE-UNIFORM base; HW adds lane*16. Global src is per-lane.
__device__ __forceinline__ void issue_tile(const float4* __restrict__ s,
                                           float4* d, int lane) {
    #pragma unroll
    for (int c = 0; c < 8; ++c)
        __builtin_amdgcn_global_load_lds(
            (const __attribute__((address_space(1))) unsigned*)(s + 64 * c + lane),
            (__attribute__((address_space(3))) unsigned*)(d + 64 * c), 16, 0, 0);
    if (lane < 8)
        __builtin_amdgcn_global_load_lds(
            (const __attribute__((address_space(1))) unsigned*)(s + 512 + lane),
            (__attribute__((address_space(3))) unsigned*)(d + 512), 16, 0, 0);
}

__global__ __launch_bounds__(128)
void xi_gemm(const float* __restrict__ ru, const float* __restrict__ en,
             const float* __restrict__ ruWih, const float* __restrict__ rubih,
             const float* __restrict__ enWih, const float* __restrict__ enbih,
             const uint4* __restrict__ frags, float* __restrict__ xi)
{
    const int tid  = threadIdx.x;
    const int wv   = tid >> 6;           // 2 waves/block
    const int lane = tid & 63;
    const int lr   = lane & 15;          // A-row slot / C-col
    const int lk   = lane >> 4;          // k-subblock / C-row group
    const int w    = blockIdx.x * 2 + wv;            // wave 0..4095
    const int gru  = (w >= 2048);
    const long row0 = (long)(w & 2047) * 128;        // 8 tiles x 16 rows

    const float* __restrict__ X   = gru ? en    : ru;
    const float* __restrict__ Wf  = gru ? enWih : ruWih;
    const float* __restrict__ bih = gru ? enbih : rubih;

    // ---- prologue loads FIRST in vmcnt order: B frags + bias + tail wts ----
    const uint4* __restrict__ fb = frags + gru * FRAG_U4_PER_GRU;
    short8v Bhi[2][4], Blo[2][4];
    #pragma unroll
    for (int t = 0; t < 2; ++t)
        #pragma unroll
        for (int q = 0; q < 4; ++q) {
            SU sh, sl;
            sh.u = fb[((t * 4 + q) * 2 + 0) * 64 + lane];
            sl.u = fb[((t * 4 + q) * 2 + 1) * 64 + lane];
            Bhi[t][q] = sh.v; Blo[t][q] = sl.v;
        }
    const int gv1 = (16 + lr < 30) ? 16 + lr : 0;
    const float bias0 = bih[lr];
    const float bias1 = bih[gv1];
    const float2 w0 = *(const float2*)(Wf + (long)lr  * II + 128);
    const float2 w1 = *(const float2*)(Wf + (long)gv1 * II + 128);

    // ---- double-buffered per-wave LDS (linear, zero-conflict per r7) ----
    __shared__ __align__(16) float ldsbuf[2][2][16 * II];  // 33,280 B/block
    float4* Bu[2] = { (float4*)ldsbuf[wv][0], (float4*)ldsbuf[wv][1] };

    const float4* __restrict__ src = (const float4*)(X + row0 * II);
    const long gb = (long)gru * ROWS_PER_GRU;

    issue_tile(src, Bu[0], lane);               // gll tile 0 (9 ops)
    issue_tile(src + 520, Bu[1], lane);         // gll tile 1 (9 ops)

    #pragma unroll
    for (int t = 0; t < 8; ++t) {
        // counted wait: tile t's 9 loads complete; keep the rest in flight
        if (t == 0)      VMWAIT(9);
        else if (t == 7) VMWAIT(8);
        else             VMWAIT(17);            // 9 loads + 8 stores in flight

        const float* __restrict__ buf = (const float*)ldsbuf[wv][t & 1];

        // ds_reads for the whole tile into registers
        float2 A[4][4];
        #pragma unroll
        for (int q = 0; q < 4; ++q) {
            const float* __restrict__ ap = buf + lr * II + 32 * q + 8 * lk;
            #pragma unroll
            for (int j = 0; j < 4; ++j) A[q][j] = *(const float2*)(ap + 2 * j);
        }
        float2 tl[4];
        #pragma unroll
        for (int r = 0; r < 4; ++r)
            tl[r] = *(const float2*)(buf + (4 * lk + r) * II + 128);

        LGKMWAIT0;                               // reads done before overwrite

        if (t + 2 < 8)                           // refill just-consumed buffer
            issue_tile(src + 520 * (t + 2), Bu[t & 1], lane);

        // ---- compute: 24 MFMA, 3-term bf16 emulation (verified r6-r10) ----
        f32x4 a0 = (f32x4){bias0, bias0, bias0, bias0};
        f32x4 a1 = (f32x4){bias1, bias1, bias1, bias1};
        #pragma unroll
        for (int q = 0; q < 4; ++q) {
            short8v ahi, alo;
            split4(A[q], ahi, alo);
            a0 = MFMA16(ahi, Bhi[0][q], a0);
            a0 = MFMA16(ahi, Blo[0][q], a0);
            a0 = MFMA16(alo, Bhi[0][q], a0);
            a1 = MFMA16(ahi, Bhi[1][q], a1);
            a1 = MFMA16(ahi, Blo[1][q], a1);
            a1 = MFMA16(alo, Bhi[1][q], a1);
        }

        // ---- k-tail + store. C: col=lr, row-in-tile=4*lk+r ----
        #pragma unroll
        for (int r = 0; r < 4; ++r) {
            const long rr = row0 + 16 * t + 4 * lk + r;
            float* __restrict__ xo = xi + (gb + rr) * 30;
            xo[lr] = a0[r] + tl[r].x * w0.x + tl[r].y * w0.y;
            if (lr < 14)
                xo[16 + lr] = a1[r] + tl[r].x * w1.x + tl[r].y * w1.y;
        }
    }
}

// ---------------- Phase 2: recurrent scan (r7 version) ----------------
__global__ __launch_bounds__(256, 4)
void gru_scan(const float* __restrict__ xi,
              const float* __restrict__ ruWhh, const float* __restrict__ rubhh,
              const float* __restrict__ enWhh, const float* __restrict__ enbhh,
              const float* __restrict__ W1, const float* __restrict__ b1,
              const float* __restrict__ W2, const float* __restrict__ b2,
              float* __restrict__ out)
{
    const int tid  = threadIdx.x;
    const int wv   = tid >> 6;
    const int lane = tid & 63;
    const int c    = lane >> 5;
    const int k    = lane & 31;
    const int kq   = (k < 10) ? k : 0;
    const int chain = (blockIdx.x * 4 + wv) * 2 + c;
    const int gru   = chain >> 11;
    const int b     = chain & (BB - 1);

    const float* __restrict__ Whh = gru ? enWhh : ruWhh;
    const float* __restrict__ bhh = gru ? enbhh : rubhh;

    float whhR[10], whhZ[10], whhN[10];
    #pragma unroll
    for (int j = 0; j < 10; ++j) {
        whhR[j] = Whh[kq * 10 + j];
        whhZ[j] = Whh[(10 + kq) * 10 + j];
        whhN[j] = Whh[(20 + kq) * 10 + j];
    }
    const float bR = bhh[kq], bZ = bhh[10 + kq], bN = bhh[20 + kq];

    __shared__ __align__(16) float lds[4][32];
    float* __restrict__ H = lds[wv] + c * 16;
    if (k < 12) H[k] = 0.f;
    float hown = 0.f;

    const float* __restrict__ xrow =
        xi + ((long)gru * ROWS_PER_GRU + (long)b * TT) * 30;

    float xR0 = xrow[kq],      xZ0 = xrow[10 + kq],  xN0 = xrow[20 + kq];
    float xR1 = xrow[30 + kq], xZ1 = xrow[40 + kq],  xN1 = xrow[50 + kq];

    for (int t = 0; t < TT; ++t) {
        const float xR = xR0, xZ = xZ0, xN = xN0;
        xR0 = xR1; xZ0 = xZ1; xN0 = xN1;
        {
            const int tn = (t + 2 < TT) ? t + 2 : TT - 1;
            const float* __restrict__ xp = xrow + (long)tn * 30;
            xR1 = xp[kq]; xZ1 = xp[10 + kq]; xN1 = xp[20 + kq];
        }

        const float4 h03 = *(const float4*)(H);
        const float4 h47 = *(const float4*)(H + 4);
        const float2 h89 = *(const float2*)(H + 8);

        float gr = bR, gz = bZ, gn = bN;
        gr = fmaf(whhR[0], h03.x, gr); gz = fmaf(whhZ[0], h03.x, gz); gn = fmaf(whhN[0], h03.x, gn);
        gr = fmaf(whhR[1], h03.y, gr); gz = fmaf(whhZ[1], h03.y, gz); gn = fmaf(whhN[1], h03.y, gn);
        gr = fmaf(whhR[2], h03.z, gr); gz = fmaf(whhZ[2], h03.z, gz); gn = fmaf(whhN[2], h03.z, gn);
        gr = fmaf(whhR[3], h03.w, gr); gz = fmaf(whhZ[3], h03.w, gz); gn = fmaf(whhN[3], h03.w, gn);
        gr = fmaf(whhR[4], h47.x, gr); gz = fmaf(whhZ[4], h47.x, gz); gn = fmaf(whhN[4], h47.x, gn);
        gr = fmaf(whhR[5], h47.y, gr); gz = fmaf(whhZ[5], h47.y, gz); gn = fmaf(whhN[5], h47.y, gn);
        gr = fmaf(whhR[6], h47.z, gr); gz = fmaf(whhZ[6], h47.z, gz); gn = fmaf(whhN[6], h47.z, gn);
        gr = fmaf(whhR[7], h47.w, gr); gz = fmaf(whhZ[7], h47.w, gz); gn = fmaf(whhN[7], h47.w, gn);
        gr = fmaf(whhR[8], h89.x, gr); gz = fmaf(whhZ[8], h89.x, gz); gn = fmaf(whhN[8], h89.x, gn);
        gr = fmaf(whhR[9], h89.y, gr); gz = fmaf(whhZ[9], h89.y, gz); gn = fmaf(whhN[9], h89.y, gn);

        const float r = sigmoidf_fast(xR + gr);
        const float z = sigmoidf_fast(xZ + gz);
        const float n = tanhf_fast(xN + r * gn);
        hown = fmaf(z, hown - n, n);
        if (k < 10) H[k] = hown;
    }

    float val = 0.f;
    if (k < 10) {
        float v = 0.f;
        #pragma unroll
        for (int d = 0; d < 20; ++d)
            v = fmaf(W2[d], W1[d * 20 + gru * 10 + k], v);
        val = v * hown;
        if (k == 0 && gru == 0) {
            float c0 = b2[0];
            #pragma unroll
            for (int d = 0; d < 20; ++d) c0 = fmaf(W2[d], b1[d], c0);
            val += c0;
        }
    }
    val += __shfl_xor(val, 8);
    val += __shfl_xor(val, 4);
    val += __shfl_xor(val, 2);
    val += __shfl_xor(val, 1);
    if (k == 0) atomicAdd(&out[b], val);
}

// ---------------- Fallback: monolithic kernel ----------------
__global__ __launch_bounds__(256, 4)
void gru_fused(const float* __restrict__ ru, const float* __restrict__ en,
               const float* __restrict__ ruWih, const float* __restrict__ ruWhh,
               const float* __restrict__ rubih, const float* __restrict__ rubhh,
               const float* __restrict__ enWih, const float* __restrict__ enWhh,
               const float* __restrict__ enbih, const float* __restrict__ enbhh,
               const float* __restrict__ W1, const float* __restrict__ b1,
               const float* __restrict__ W2, const float* __restrict__ b2,
               float* __restrict__ out)
{
    const int tid  = threadIdx.x;
    const int wv   = tid >> 6;
    const int lane = tid & 63;
    const int g    = lane & 31;
    const int h    = lane >> 5;
    const int wid  = blockIdx.x * 4 + wv;
    const int gru  = wid >> 11;
    const int b    = wid & (BB - 1);

    const float* __restrict__ x   = gru ? en    : ru;
    const float* __restrict__ Wih = gru ? enWih : ruWih;
    const float* __restrict__ Whh = gru ? enWhh : ruWhh;
    const float* __restrict__ bih = gru ? enbih : rubih;
    const float* __restrict__ bhh = gru ? enbhh : rubhh;

    __shared__ __align__(16) float lds[4][176];
    float* __restrict__ X    = lds[wv];
    float* __restrict__ PRE  = X + 132;
    float* __restrict__ Hbuf = X + 164;

    const int gq = (g < 30) ? g : 0;
    float wih[64];
    #pragma unroll
    for (int j = 0; j < 64; ++j) wih[j] = Wih[gq * II + h * 64 + j];
    const float w_e = Wih[gq * II + 128 + h];
    float whh[10];
    #pragma unroll
    for (int k = 0; k < 10; ++k) whh[k] = Whh[gq * 10 + k];
    const float bihg = bih[gq];
    const float bhhg = bhh[gq];

    if (lane < 12) Hbuf[lane] = 0.f;
    float hown = 0.f;

    const float* __restrict__ xrow = x + (size_t)b * (TT * II);
    float xa = xrow[lane];
    float xb = xrow[64 + lane];
    float xc = (lane < 2) ? xrow[128 + lane] : 0.f;

    for (int t = 0; t < TT; ++t) {
        X[lane] = xa;
        X[64 + lane] = xb;
        if (lane < 2) X[128 + lane] = xc;
        {
            const int tn = (t < TT - 1) ? t + 1 : t;
            const float* __restrict__ xn = xrow + (size_t)tn * II;
            xa = xn[lane];
            xb = xn[64 + lane];
            xc = (lane < 2) ? xn[128 + lane] : 0.f;
        }
        const float4 h03 = *(const float4*)(Hbuf);
        const float4 h47 = *(const float4*)(Hbuf + 4);
        const float2 h89 = *(const float2*)(Hbuf + 8);
        float gh0 = fmaf(whh[0], h03.x, bhhg);
        float gh1 = whh[1] * h03.y;
        gh0 = fmaf(whh[2], h03.z, gh0);
        gh1 = fmaf(whh[3], h03.w, gh1);
        gh0 = fmaf(whh[4], h47.x, gh0);
        gh1 = fmaf(whh[5], h47.y, gh1);
        gh0 = fmaf(whh[6], h47.z, gh0);
        gh1 = fmaf(whh[7], h47.w, gh1);
        gh0 = fmaf(whh[8], h89.x, gh0);
        gh1 = fmaf(whh[9], h89.y, gh1);
        const float gh = gh0 + gh1;

        float s0 = 0.f, s1 = 0.f, s2 = 0.f, s3 = 0.f;
        const float4* __restrict__ xb4 = (const float4*)(X + h * 64);
        #pragma unroll
        for (int c = 0; c < 16; ++c) {
            const float4 v = xb4[c];
            s0 = fmaf(wih[4 * c + 0], v.x, s0);
            s1 = fmaf(wih[4 * c + 1], v.y, s1);
            s2 = fmaf(wih[4 * c + 2], v.z, s2);
            s3 = fmaf(wih[4 * c + 3], v.w, s3);
        }
        float s = (s0 + s1) + (s2 + s3);
        s = fmaf(w_e, X[128 + h], s);
        s += __shfl_xor(s, 32);

        const float xiv = s + bihg;
        const float pre = xiv + gh;
        if (lane < 30) PRE[lane] = pre;
        const float rpre = PRE[(g - 20) & 31];
        const float zpre = PRE[(g - 10) & 31];
        const float r = sigmoidf_fast(rpre);
        const float z = sigmoidf_fast(zpre);
        const float n = tanhf_fast(xiv + r * gh);
        const float hnew = (1.f - z) * n + z * hown;
        hown = hnew;
        if (lane >= 20 && lane < 30) Hbuf[lane - 20] = hnew;
    }

    float val = 0.f;
    if (lane < 10) {
        const float hk = Hbuf[lane];
        float v = 0.f;
        #pragma unroll
        for (int d = 0; d < 20; ++d)
            v = fmaf(W2[d], W1[d * 20 + gru * 10 + lane], v);
        val = v * hk;
        if (lane == 0 && gru == 0) {
            float c0 = b2[0];
            #pragma unroll
            for (int d = 0; d < 20; ++d) c0 = fmaf(W2[d], b1[d], c0);
            val += c0;
        }
    }
    #pragma unroll
    for (int o = 32; o > 0; o >>= 1) val += __shfl_xor(val, o);
    if (lane == 0) atomicAdd(&out[b], val);
}

extern "C" void kernel_launch(void* const* d_in, const int* in_sizes, int n_in,
                              void* d_out, int out_size, void* d_ws, size_t ws_size,
                              hipStream_t stream) {
    (void)in_sizes; (void)n_in;
    const float* ru    = (const float*)d_in[0];
    const float* en    = (const float*)d_in[1];
    const float* ruWih = (const float*)d_in[2];
    const float* ruWhh = (const float*)d_in[3];
    const float* rubih = (const float*)d_in[4];
    const float* rubhh = (const float*)d_in[5];
    const float* enWih = (const float*)d_in[6];
    const float* enWhh = (const float*)d_in[7];
    const float* enbih = (const float*)d_in[8];
    const float* enbhh = (const float*)d_in[9];
    const float* W1    = (const float*)d_in[10];
    const float* b1    = (const float*)d_in[11];
    const float* W2    = (const float*)d_in[12];
    const float* b2    = (const float*)d_in[13];
    float* out = (float*)d_out;

    hipMemsetAsync(d_out, 0, (size_t)out_size * sizeof(float), stream);

    const size_t frag_bytes = 2 * FRAG_U4_PER_GRU * sizeof(uint4);  // 32 KB
    if (ws_size >= XI_BYTES + frag_bytes) {
        float* xi = (float*)d_ws;
        uint4* frags = (uint4*)((char*)d_ws + XI_BYTES);
        prep_w<<<dim3(1), dim3(128), 0, stream>>>(ruWih, enWih, frags);
        // 4096 waves x 8 tiles x 16 rows; 2 waves/block -> 2048 blocks
        xi_gemm<<<dim3(2048), dim3(128), 0, stream>>>(
            ru, en, ruWih, rubih, enWih, enbih, frags, xi);
        gru_scan<<<dim3(512), dim3(256), 0, stream>>>(
            xi, ruWhh, rubhh, enWhh, enbhh, W1, b1, W2, b2, out);
    } else {
        gru_fused<<<dim3(1024), dim3(256), 0, stream>>>(
            ru, en, ruWih, ruWhh, rubih, rubhh,
            enWih, enWhh, enbih, enbhh, W1, b1, W2, b2, out);
    }
}